// Round 6
// baseline (434.087 us; speedup 1.0000x reference)
//
#include <hip/hip_runtime.h>
#include <math.h>

#define NB 16
#define NA 8400
#define NG 128
#define NC 5
#define KTOP 10
#define MAXF 5

// f64 log-sigmoid, bit-identical to the reference chain (rounds 2/3 passed with this)
static __device__ __forceinline__ double lgs64_of(float x) {
    double s = 1.0 / (1.0 + exp(-(double)x));
    s = fmin(fmax(s, 1e-9), 1.0);
    return log(s + 1e-9);
}

// order-preserving f32 <-> u32 encoding (for atomicMax on signed floats)
static __device__ __forceinline__ unsigned fenc(float f) {
    unsigned u = __float_as_uint(f);
    return (u & 0x80000000u) ? ~u : (u | 0x80000000u);
}
static __device__ __forceinline__ float fdec(unsigned e) {
    return (e & 0x80000000u) ? __uint_as_float(e ^ 0x80000000u) : __uint_as_float(~e);
}

// ---------- K0: f32 log-sigmoid table + zero pos_mask ----------

__global__ __launch_bounds__(256) void k_prep(
    const float* __restrict__ ps, float* __restrict__ tab, int* __restrict__ pos_mask)
{
    int i = blockIdx.x * 256 + threadIdx.x;
    if (i < NB * NA * NC) {
        float x = ps[i];
        float s = 1.0f / (1.0f + __expf(-x));
        s = fminf(fmaxf(s, 1e-9f), 1.0f);
        tab[i] = __logf(s + 1e-9f);
    }
    if (i < NB * NA) pos_mask[i] = 0;
}

// ---------- K1: per-gt fallback + top-10 + dynamic_k + pos bits + am_max ----------

__global__ __launch_bounds__(256) void k_assign(
    const float* __restrict__ pred_scores,
    const float* __restrict__ pred_bboxes,
    const float* __restrict__ anchor_points,
    const int*   __restrict__ gt_labels,
    const float* __restrict__ gt_bboxes,
    const int*   __restrict__ mask_gt,
    const float* __restrict__ lg32,
    int* __restrict__ fb_cnt,
    int* __restrict__ fb_idx,
    double* __restrict__ am_max,
    int* __restrict__ pos_mask)
{
    int bg = blockIdx.x;
    int b = bg / NG;
    int tid = threadIdx.x;
    int lane = tid & 63;
    int wid = tid >> 6;

    const float* gbb = gt_bboxes + (size_t)bg * 5;
    float cxf = gbb[0], cyf = gbb[1];
    double cx = cxf, cy = cyf, w = gbb[2], h = gbb[3], th = gbb[4];
    double ct = cos(-th), st = sin(-th);
    double w15 = w * 1.5, h15 = h * 1.5;
    int m = mask_gt[bg];
    double area = w * h;

    __shared__ unsigned s_bar_u;
    __shared__ double LwV[4][KTOP];
    __shared__ int    LwI[4][KTOP];
    __shared__ double wv_s[KTOP];
    __shared__ int    wi_s[KTOP];
    __shared__ int    s_win[MAXF];
    __shared__ int    s_k;
    __shared__ int    s_cnt;

    bool need_fb = (m > 0) && (area < 0.01);
    if (tid == 0) { s_k = 0; s_cnt = 0; s_bar_u = 0u; }
    __syncthreads();

    // ---- fallback phase (rare) ----
    if (need_fb) {
        int cnt = 0;
        double ld[MAXF]; int lid[MAXF];
#pragma unroll
        for (int t = 0; t < MAXF; t++) { ld[t] = 1e300; lid[t] = 0x7fffffff; }
        for (int a = tid; a < NA; a += 256) {
            float axf = anchor_points[2 * a], ayf = anchor_points[2 * a + 1];
            double cdx = (double)axf - cx, cdy = (double)ayf - cy;
            double ldx = cdx * ct - cdy * st;
            double ldy = cdx * st + cdy * ct;
            if (fabs(ldx) < w15 && fabs(ldy) < h15) cnt++;
            double d = sqrt(cdx * cdx + cdy * cdy);
            double cv = d; int ci = a;
#pragma unroll
            for (int p = 0; p < MAXF; p++) {
                bool better = (cv < ld[p]) || (cv == ld[p] && ci < lid[p]);
                double tv = ld[p]; int ti = lid[p];
                if (better) { ld[p] = cv; lid[p] = ci; cv = tv; ci = ti; }
            }
        }
        for (int off = 32; off; off >>= 1) cnt += __shfl_xor(cnt, off);
        if (lane == 0) atomicAdd(&s_cnt, cnt);
        for (int j = 0; j < MAXF; j++) {
            double bv = ld[0]; int bi = lid[0];
            int hi = lid[0];
            for (int off = 32; off; off >>= 1) {
                double ov = __shfl_xor(bv, off); int oi = __shfl_xor(bi, off);
                if (ov < bv || (ov == bv && oi < bi)) { bv = ov; bi = oi; }
            }
            if (lane == 0) { LwV[wid][j] = bv; LwI[wid][j] = bi; }
            if (hi == bi) {
#pragma unroll
                for (int p = 0; p < MAXF - 1; p++) { ld[p] = ld[p + 1]; lid[p] = lid[p + 1]; }
                ld[MAXF - 1] = 1e301; lid[MAXF - 1] = 0x7fffffff;
            }
        }
        __syncthreads();
        if (tid == 0) {
            int p0 = 0, p1 = 0, p2 = 0, p3 = 0;
            for (int j = 0; j < MAXF; j++) {
                double h0 = (p0 < MAXF) ? LwV[0][p0] : 1e302; int i0 = (p0 < MAXF) ? LwI[0][p0] : 0x7fffffff;
                double h1 = (p1 < MAXF) ? LwV[1][p1] : 1e302; int i1 = (p1 < MAXF) ? LwI[1][p1] : 0x7fffffff;
                double h2 = (p2 < MAXF) ? LwV[2][p2] : 1e302; int i2 = (p2 < MAXF) ? LwI[2][p2] : 0x7fffffff;
                double h3 = (p3 < MAXF) ? LwV[3][p3] : 1e302; int i3 = (p3 < MAXF) ? LwI[3][p3] : 0x7fffffff;
                double bv = h0; int bi = i0; int bw = 0;
                if (h1 < bv || (h1 == bv && i1 < bi)) { bv = h1; bi = i1; bw = 1; }
                if (h2 < bv || (h2 == bv && i2 < bi)) { bv = h2; bi = i2; bw = 2; }
                if (h3 < bv || (h3 == bv && i3 < bi)) { bv = h3; bi = i3; bw = 3; }
                s_win[j] = bi;
                if (bw == 0) p0++; else if (bw == 1) p1++; else if (bw == 2) p2++; else p3++;
            }
            int total = s_cnt;
            int k = 0;
            if (total == 0) k = (area < 0.002) ? 5 : 3;
            s_k = k;
            for (int j = 0; j < MAXF; j++) fb_idx[bg * MAXF + j] = s_win[j];
        }
        __syncthreads();
    }
    if (tid == 0) fb_cnt[bg] = s_k;

    if (m <= 0) {
        if (tid == 0) am_max[bg] = 0.0;
        return;
    }
    __syncthreads();

    double scale = sqrt(w * h);
    float scalef = (float)scale;
    float sef = scalef + 1e-6f;
    float se2f = scalef * 1.5f + 1e-6f;
    int lbl = gt_labels[bg];
    int fcnt = s_k;
    int fidx[MAXF];
#pragma unroll
    for (int t = 0; t < MAXF; t++) fidx[t] = need_fb ? s_win[t] : 0x7fffffff;

    // ---- Phase A: f32 t-domain lower bounds -> block bar ----
    unsigned long long inmask = 0ull;
    float lb10[KTOP];
#pragma unroll
    for (int t = 0; t < KTOP; t++) lb10[t] = -3.0e38f;

    {
        int i = 0;
        for (int a = tid; a < NA; a += 256, ++i) {
            float axf = anchor_points[2 * a], ayf = anchor_points[2 * a + 1];
            double cdx = (double)axf - cx, cdy = (double)ayf - cy;
            double ldx = cdx * ct - cdy * st;
            double ldy = cdx * st + cdy * ct;
            bool inb = (fabs(ldx) < w15) && (fabs(ldy) < h15);
            bool fbh = false;
#pragma unroll
            for (int t = 0; t < MAXF; t++) if (t < fcnt && fidx[t] == a) fbh = true;
            if (inb || fbh) {
                inmask |= (1ull << i);
                float pxf = pred_bboxes[((size_t)b * NA + a) * 5 + 0];
                float pyf = pred_bboxes[((size_t)b * NA + a) * 5 + 1];
                float lgsf = lg32[((size_t)b * NA + a) * NC + lbl];
                float dxf = pxf - cxf, dyf = pyf - cyf;
                float rf = sqrtf(dxf * dxf + dyf * dyf) / sef;
                float e1f = __expf(-(rf * rf));
                float Lf = __logf(e1f + 1e-9f);
                float cdxf = axf - cxf, cdyf = ayf - cyf;
                float crf = sqrtf(cdxf * cdxf + cdyf * cdyf) / se2f;
                float t1 = 0.5f * lgsf, t2 = 6.0f * Lf, t3 = crf * crf;
                float t32 = t1 + t2 - t3;
                float mm = 2e-4f + 2e-5f * (fabsf(t1) + fabsf(t2) + t3);
                float cv = t32 - mm;
#pragma unroll
                for (int p = 0; p < KTOP; p++) {
                    bool better = cv > lb10[p];
                    float tv = lb10[p];
                    if (better) { lb10[p] = cv; cv = tv; }
                }
            }
        }
    }
    atomicMax(&s_bar_u, fenc(lb10[KTOP - 1]));
    __syncthreads();
    float bar_t = fdec(s_bar_u);
    bool skip_ok = (bar_t > -700.0f);   // false also when bar unfilled (NaN decode)

    // ---- Phase B: f64 eval of survivors only ----
    double lv[KTOP]; int li[KTOP];
#pragma unroll
    for (int t = 0; t < KTOP; t++) { lv[t] = -1.0; li[t] = 0x7fffffff; }

    {
        int i = 0;
        for (int a = tid; a < NA; a += 256, ++i) {
            bool act = (inmask >> i) & 1ull;
            double amm; bool have = false;
            if (act) {
                float axf = anchor_points[2 * a], ayf = anchor_points[2 * a + 1];
                float pxf = pred_bboxes[((size_t)b * NA + a) * 5 + 0];
                float pyf = pred_bboxes[((size_t)b * NA + a) * 5 + 1];
                bool do_eval = true;
                if (skip_ok) {
                    float lgsf = lg32[((size_t)b * NA + a) * NC + lbl];
                    float dxf = pxf - cxf, dyf = pyf - cyf;
                    float rf = sqrtf(dxf * dxf + dyf * dyf) / sef;
                    float e1f = __expf(-(rf * rf));
                    float Lf = __logf(e1f + 1e-9f);
                    float cdxf = axf - cxf, cdyf = ayf - cyf;
                    float crf = sqrtf(cdxf * cdxf + cdyf * cdyf) / se2f;
                    float t1 = 0.5f * lgsf, t2 = 6.0f * Lf, t3 = crf * crf;
                    float t32 = t1 + t2 - t3;
                    float mm = 2e-4f + 2e-5f * (fabsf(t1) + fabsf(t2) + t3);
                    if (t32 + mm < bar_t) do_eval = false;   // provably below top-10
                }
                if (do_eval) {
                    double lgs = lgs64_of(pred_scores[((size_t)b * NA + a) * NC + lbl]);
                    double px = (double)pxf, py = (double)pyf;
                    double dx = px - cx, dy = py - cy;
                    double d  = sqrt(dx * dx + dy * dy);
                    double r  = d / (scale + 1e-6);
                    double e1 = exp(-(r * r));
                    double L  = log(e1 + 1e-9);
                    double cdx = (double)axf - cx, cdy = (double)ayf - cy;
                    double cd = sqrt(cdx * cdx + cdy * cdy);
                    double cr = cd / (scale * 1.5 + 1e-6);
                    amm = exp(0.5 * lgs + 6.0 * L - cr * cr);
                    have = true;
                }
            } else if (!skip_ok) {
                amm = 0.0; have = true;   // zeros compete only when <10 certified positives
            }
            if (have) {
                double cv = amm; int ci = a;
#pragma unroll
                for (int p = 0; p < KTOP; p++) {
                    bool better = (cv > lv[p]) || (cv == lv[p] && ci < li[p]);
                    double tv = lv[p]; int ti = li[p];
                    if (better) { lv[p] = cv; li[p] = ci; cv = tv; ci = ti; }
                }
            }
        }
    }

    // wave merge (desc, idx asc)
    for (int j = 0; j < KTOP; j++) {
        double bv = lv[0]; int bi = li[0];
        int hi = li[0];
        for (int off = 32; off; off >>= 1) {
            double ov = __shfl_xor(bv, off); int oi = __shfl_xor(bi, off);
            if (ov > bv || (ov == bv && oi < bi)) { bv = ov; bi = oi; }
        }
        if (lane == 0) { LwV[wid][j] = bv; LwI[wid][j] = bi; }
        if (hi == bi) {
#pragma unroll
            for (int p = 0; p < KTOP - 1; p++) { lv[p] = lv[p + 1]; li[p] = li[p + 1]; }
            lv[KTOP - 1] = -2.0; li[KTOP - 1] = 0x7fffffff;
        }
    }
    __syncthreads();

    if (tid == 0) {
        int p0 = 0, p1 = 0, p2 = 0, p3 = 0;
        for (int j = 0; j < KTOP; j++) {
            double h0 = (p0 < KTOP) ? LwV[0][p0] : -3.0; int i0 = (p0 < KTOP) ? LwI[0][p0] : 0x7fffffff;
            double h1 = (p1 < KTOP) ? LwV[1][p1] : -3.0; int i1 = (p1 < KTOP) ? LwI[1][p1] : 0x7fffffff;
            double h2 = (p2 < KTOP) ? LwV[2][p2] : -3.0; int i2 = (p2 < KTOP) ? LwI[2][p2] : 0x7fffffff;
            double h3 = (p3 < KTOP) ? LwV[3][p3] : -3.0; int i3 = (p3 < KTOP) ? LwI[3][p3] : 0x7fffffff;
            double bv = h0; int bi = i0; int bw = 0;
            if (h1 > bv || (h1 == bv && i1 < bi)) { bv = h1; bi = i1; bw = 1; }
            if (h2 > bv || (h2 == bv && i2 < bi)) { bv = h2; bi = i2; bw = 2; }
            if (h3 > bv || (h3 == bv && i3 < bi)) { bv = h3; bi = i3; bw = 3; }
            wv_s[j] = bv; wi_s[j] = bi;
            if (bw == 0) p0++; else if (bw == 1) p1++; else if (bw == 2) p2++; else p3++;
        }
        am_max[bg] = wv_s[0];
        double ssum = 0.0;
        for (int j = 0; j < KTOP; j++) {
            int aW = wi_s[j];
            double px = (double)pred_bboxes[((size_t)b * NA + aW) * 5 + 0];
            double py = (double)pred_bboxes[((size_t)b * NA + aW) * 5 + 1];
            double dx = px - cx, dy = py - cy;
            double d = sqrt(dx * dx + dy * dy);
            double r = d / (scale + 1e-6);
            ssum += exp(-(r * r));
        }
        double rk = rint(ssum);
        rk = fmin(fmax(rk, 1.0), 10.0);
        for (int j = 0; j < KTOP; j++) {
            if (wv_s[j] > 1e-9 && (double)j < rk)
                atomicOr(&pos_mask[b * NA + wi_s[j]], 1);
        }
    }
}

// ---------- K2: per-anchor argmax (g-sliced) two-phase + outputs ----------

__global__ __launch_bounds__(256) void k_final(
    const float* __restrict__ pred_scores,
    const float* __restrict__ pred_bboxes,
    const float* __restrict__ anchor_points,
    const int*   __restrict__ gt_labels,
    const float* __restrict__ gt_bboxes,
    const int*   __restrict__ mask_gt,
    const float* __restrict__ lg32,
    const int*   __restrict__ fb_cnt,
    const int*   __restrict__ fb_idx,
    const double* __restrict__ am_max,
    const int*   __restrict__ pos_mask,
    float* __restrict__ out)
{
    __shared__ double s_cx[NG], s_cy[NG], s_ct[NG], s_st[NG], s_scale[NG], s_w15[NG], s_h15[NG], s_am[NG];
    __shared__ float  f_cx[NG], f_cy[NG], f_se[NG], f_se2[NG];
    __shared__ int s_lbl[NG], s_msk[NG], s_fcnt[NG];
    __shared__ int s_fidx[NG][MAXF];
    __shared__ double mv[4][64];
    __shared__ int    mg[4][64];
    __shared__ double mo[4][64];
    __shared__ float  barr[4][64];

    int b = blockIdx.y;
    int tid = threadIdx.x;
    if (tid < NG) {
        int g = tid, bgi = b * NG + g;
        const float* gbb = gt_bboxes + (size_t)bgi * 5;
        double th = gbb[4];
        double w = gbb[2], h = gbb[3];
        s_cx[g] = gbb[0]; s_cy[g] = gbb[1];
        s_w15[g] = w * 1.5; s_h15[g] = h * 1.5;
        s_ct[g] = cos(-th); s_st[g] = sin(-th);
        double sc = sqrt(w * h);
        s_scale[g] = sc;
        f_cx[g] = gbb[0]; f_cy[g] = gbb[1];
        float scf = (float)sc;
        f_se[g] = scf + 1e-6f; f_se2[g] = scf * 1.5f + 1e-6f;
        s_am[g] = am_max[bgi];
        s_lbl[g] = gt_labels[bgi];
        s_msk[g] = mask_gt[bgi];
        s_fcnt[g] = fb_cnt[bgi];
        for (int t = 0; t < MAXF; t++) s_fidx[g][t] = fb_idx[bgi * MAXF + t];
    }
    __syncthreads();

    int al = tid & 63;
    int slice = tid >> 6;
    int g0 = slice * 32;
    int a = blockIdx.x * 64 + al;
    bool okA = (a < NA);

    float pxf = 0.f, pyf = 0.f, axf = 0.f, ayf = 0.f;
    float l0 = 0.f, l1 = 0.f, l2 = 0.f, l3 = 0.f, l4 = 0.f;
    unsigned actmask = 0u;
    float bestlb = -3.0e38f;

    if (okA) {
        pxf = pred_bboxes[((size_t)b * NA + a) * 5 + 0];
        pyf = pred_bboxes[((size_t)b * NA + a) * 5 + 1];
        axf = anchor_points[2 * a]; ayf = anchor_points[2 * a + 1];
        const float* lg = lg32 + ((size_t)b * NA + a) * NC;
        l0 = lg[0]; l1 = lg[1]; l2 = lg[2]; l3 = lg[3]; l4 = lg[4];

        // Phase A: f32 bounds over this slice's 32 gts
        for (int k = 0; k < 32; k++) {
            int g = g0 + k;
            double cdx = (double)axf - s_cx[g], cdy = (double)ayf - s_cy[g];
            double ldx = cdx * s_ct[g] - cdy * s_st[g];
            double ldy = cdx * s_st[g] + cdy * s_ct[g];
            bool inb = (fabs(ldx) < s_w15[g]) && (fabs(ldy) < s_h15[g]);
            bool fbh = false;
            int fc = s_fcnt[g];
#pragma unroll
            for (int t = 0; t < MAXF; t++) if (t < fc && s_fidx[g][t] == a) fbh = true;
            if ((inb || fbh) && s_msk[g] > 0) {
                actmask |= (1u << k);
                int lbl = s_lbl[g];
                float lgsf = (lbl == 0) ? l0 : (lbl == 1) ? l1 : (lbl == 2) ? l2 : (lbl == 3) ? l3 : l4;
                float dxf = pxf - f_cx[g], dyf = pyf - f_cy[g];
                float rf = sqrtf(dxf * dxf + dyf * dyf) / f_se[g];
                float e1f = __expf(-(rf * rf));
                float Lf = __logf(e1f + 1e-9f);
                float cdxf = axf - f_cx[g], cdyf = ayf - f_cy[g];
                float crf = sqrtf(cdxf * cdxf + cdyf * cdyf) / f_se2[g];
                float t1 = 0.5f * lgsf, t2 = 6.0f * Lf, t3 = crf * crf;
                float t32 = t1 + t2 - t3;
                float mm = 2e-4f + 2e-5f * (fabsf(t1) + fabsf(t2) + t3);
                bestlb = fmaxf(bestlb, t32 - mm);
            }
        }
    }
    barr[slice][al] = bestlb;
    __syncthreads();
    float bar_a = fmaxf(fmaxf(barr[0][al], barr[1][al]), fmaxf(barr[2][al], barr[3][al]));
    bool skip_ok = (bar_a > -700.0f);

    double best = 0.0; int bestg = g0; double bov = 0.0;
    if (okA) {
        // Phase B: f64 eval of surviving gts, ascending g (first-max semantics)
        for (int k = 0; k < 32; k++) {
            if (!((actmask >> k) & 1u)) continue;
            int g = g0 + k;
            if (skip_ok) {
                int lbl = s_lbl[g];
                float lgsf = (lbl == 0) ? l0 : (lbl == 1) ? l1 : (lbl == 2) ? l2 : (lbl == 3) ? l3 : l4;
                float dxf = pxf - f_cx[g], dyf = pyf - f_cy[g];
                float rf = sqrtf(dxf * dxf + dyf * dyf) / f_se[g];
                float e1f = __expf(-(rf * rf));
                float Lf = __logf(e1f + 1e-9f);
                float cdxf = axf - f_cx[g], cdyf = ayf - f_cy[g];
                float crf = sqrtf(cdxf * cdxf + cdyf * cdyf) / f_se2[g];
                float t1 = 0.5f * lgsf, t2 = 6.0f * Lf, t3 = crf * crf;
                float t32 = t1 + t2 - t3;
                float mm = 2e-4f + 2e-5f * (fabsf(t1) + fabsf(t2) + t3);
                if (t32 + mm < bar_a) continue;   // provably below the anchor's max
            }
            int lbl = s_lbl[g];
            double lgs = lgs64_of(pred_scores[((size_t)b * NA + a) * NC + lbl]);
            double px = (double)pxf, py = (double)pyf;
            double dx = px - s_cx[g], dy = py - s_cy[g];
            double d = sqrt(dx * dx + dy * dy);
            double r = d / (s_scale[g] + 1e-6);
            double e1 = exp(-(r * r));
            double L = log(e1 + 1e-9);
            double cdx = (double)axf - s_cx[g], cdy = (double)ayf - s_cy[g];
            double cd = sqrt(cdx * cdx + cdy * cdy);
            double cr = cd / (s_scale[g] * 1.5 + 1e-6);
            double amm = exp(0.5 * lgs + 6.0 * L - cr * cr);
            if (amm > best) { best = amm; bestg = g; bov = e1; }
        }
    }

    mv[slice][al] = best; mg[slice][al] = bestg; mo[slice][al] = bov;
    __syncthreads();

    if (tid < 64) {
        int a2 = blockIdx.x * 64 + tid;
        if (a2 < NA) {
            double B = mv[0][tid]; int G = mg[0][tid]; double OV = mo[0][tid];
#pragma unroll
            for (int s = 1; s < 4; s++) {
                if (mv[s][tid] > B) { B = mv[s][tid]; G = mg[s][tid]; OV = mo[s][tid]; }
            }
            int lbl = s_lbl[G];
            bool pos = pos_mask[b * NA + a2] != 0;
            bool valid = (lbl >= 0 && lbl < NC) && pos;
            double raw = B / (s_am[G] + 1e-9) * OV;
            double soft = (raw > 0.0) ? sqrt(raw) : 0.0;

            size_t ba = (size_t)b * NA + a2;
            out[ba] = (float)lbl;
            const float* gb2 = gt_bboxes + ((size_t)b * NG + G) * 5;
            float* ob = out + (size_t)NB * NA + ba * 5;
            ob[0] = gb2[0]; ob[1] = gb2[1]; ob[2] = gb2[2]; ob[3] = gb2[3]; ob[4] = gb2[4];
            float* os = out + (size_t)NB * NA * 6 + ba * 5;
            float sval = valid ? (float)soft : 0.0f;
#pragma unroll
            for (int c = 0; c < NC; c++) os[c] = (c == lbl) ? sval : 0.0f;
            out[(size_t)NB * NA * 11 + ba] = pos ? 1.0f : 0.0f;
        }
    }
}

// ---------- launch ----------

extern "C" void kernel_launch(void* const* d_in, const int* in_sizes, int n_in,
                              void* d_out, int out_size, void* d_ws, size_t ws_size,
                              hipStream_t stream)
{
    const float* pred_scores   = (const float*)d_in[0];
    const float* pred_bboxes   = (const float*)d_in[1];
    const float* anchor_points = (const float*)d_in[2];
    const int*   gt_labels     = (const int*)d_in[3];
    const float* gt_bboxes     = (const float*)d_in[4];
    const int*   mask_gt       = (const int*)d_in[5];
    float* out = (float*)d_out;

    char* ws = (char*)d_ws;
    size_t off = 0;
    int* pos_mask = (int*)(ws + off);
    off += (size_t)NB * NA * sizeof(int);
    off = (off + 255) & ~(size_t)255;
    double* amax = (double*)(ws + off);
    off += (size_t)NB * NG * sizeof(double);
    off = (off + 255) & ~(size_t)255;
    int* fb_cnt = (int*)(ws + off);
    off += (size_t)NB * NG * sizeof(int);
    off = (off + 255) & ~(size_t)255;
    int* fb_idx = (int*)(ws + off);
    off += (size_t)NB * NG * MAXF * sizeof(int);
    off = (off + 255) & ~(size_t)255;
    float* lg32 = (float*)(ws + off);

    int nls = NB * NA * NC;
    k_prep<<<(nls + 255) / 256, 256, 0, stream>>>(pred_scores, lg32, pos_mask);
    k_assign<<<NB * NG, 256, 0, stream>>>(pred_scores, pred_bboxes, anchor_points, gt_labels,
                                          gt_bboxes, mask_gt, lg32,
                                          fb_cnt, fb_idx, amax, pos_mask);
    k_final<<<dim3((NA + 63) / 64, NB), 256, 0, stream>>>(
        pred_scores, pred_bboxes, anchor_points, gt_labels, gt_bboxes, mask_gt, lg32,
        fb_cnt, fb_idx, amax, pos_mask, out);
}

// Round 8
// 302.284 us; speedup vs baseline: 1.4360x; 1.4360x over previous
//
#include <hip/hip_runtime.h>
#include <math.h>

#define NB 16
#define NA 8400
#define NG 128
#define NC 5
#define KTOP 10
#define MAXF 5

// f64 log-sigmoid, bit-identical to the reference chain
static __device__ __forceinline__ double lgs64_of(float x) {
    double s = 1.0 / (1.0 + exp(-(double)x));
    s = fmin(fmax(s, 1e-9), 1.0);
    return log(s + 1e-9);
}

// order-preserving f32 <-> u32 encoding (for atomicMax on signed floats)
static __device__ __forceinline__ unsigned fenc(float f) {
    unsigned u = __float_as_uint(f);
    return (u & 0x80000000u) ? ~u : (u | 0x80000000u);
}
static __device__ __forceinline__ float fdec(unsigned e) {
    return (e & 0x80000000u) ? __uint_as_float(e ^ 0x80000000u) : __uint_as_float(~e);
}

// Algebraic bounds on t = 0.5*lgs + 6*log(exp(-r2)+1e-9) - cr2 — NO transcendentals.
// r2, cr2 in f32; returns lb/ub certified to contain the exact f64 t.
static __device__ __forceinline__ void t_bounds(
    float lgsf, float r2, float cr2, float& lb, float& ub)
{
    float A = -r2;
    float Llo = fmaxf(A, -20.723267f);            // log(1e-9)
    float lw = (A > -16.0f || A < -25.0f) ? 0.014f : 0.6932f;
    float base = 0.5f * lgsf + 6.0f * Llo - cr2;
    float mm = 5e-4f + 1e-5f * (fabsf(lgsf) + 6.0f * fabsf(Llo) + cr2);
    lb = base - mm;
    ub = base + 6.0f * lw + mm;
}

// ---------- K0: f32 log-sigmoid table + zero pos_mask ----------

__global__ __launch_bounds__(256) void k_prep(
    const float* __restrict__ ps, float* __restrict__ tab, int* __restrict__ pos_mask)
{
    int i = blockIdx.x * 256 + threadIdx.x;
    if (i < NB * NA * NC) {
        float x = ps[i];
        float s = 1.0f / (1.0f + __expf(-x));
        s = fminf(fmaxf(s, 1e-9f), 1.0f);
        tab[i] = __logf(s + 1e-9f);
    }
    if (i < NB * NA) pos_mask[i] = 0;
}

// ---------- K1: per-gt fallback + top-10 + dynamic_k + pos bits + am_max ----------

__global__ __launch_bounds__(256) void k_assign(
    const float* __restrict__ pred_scores,
    const float* __restrict__ pred_bboxes,
    const float* __restrict__ anchor_points,
    const int*   __restrict__ gt_labels,
    const float* __restrict__ gt_bboxes,
    const int*   __restrict__ mask_gt,
    const float* __restrict__ lg32,
    int* __restrict__ fb_cnt,
    int* __restrict__ fb_idx,
    double* __restrict__ am_max,
    int* __restrict__ pos_mask)
{
    int bg = blockIdx.x;
    int b = bg / NG;
    int tid = threadIdx.x;
    int lane = tid & 63;
    int wid = tid >> 6;

    const float* gbb = gt_bboxes + (size_t)bg * 5;
    float cxf = gbb[0], cyf = gbb[1];
    double cx = cxf, cy = cyf, w = gbb[2], h = gbb[3], th = gbb[4];
    double ct = cos(-th), st = sin(-th);
    double w15 = w * 1.5, h15 = h * 1.5;
    int m = mask_gt[bg];
    double area = w * h;

    __shared__ float  s_ub[NA];
    __shared__ unsigned s_bar_u;
    __shared__ double LwV[4][KTOP];
    __shared__ int    LwI[4][KTOP];
    __shared__ double wv_s[KTOP];
    __shared__ int    wi_s[KTOP];
    __shared__ int    s_win[MAXF];
    __shared__ int    s_k;
    __shared__ int    s_cnt;

    bool need_fb = (m > 0) && (area < 0.01);
    if (tid == 0) { s_k = 0; s_cnt = 0; s_bar_u = 0u; }
    __syncthreads();

    // ---- fallback phase (rare) ----
    if (need_fb) {
        int cnt = 0;
        double ld[MAXF]; int lid[MAXF];
#pragma unroll
        for (int t = 0; t < MAXF; t++) { ld[t] = 1e300; lid[t] = 0x7fffffff; }
        for (int a = tid; a < NA; a += 256) {
            float axf = anchor_points[2 * a], ayf = anchor_points[2 * a + 1];
            double cdx = (double)axf - cx, cdy = (double)ayf - cy;
            double ldx = cdx * ct - cdy * st;
            double ldy = cdx * st + cdy * ct;
            if (fabs(ldx) < w15 && fabs(ldy) < h15) cnt++;
            double d = sqrt(cdx * cdx + cdy * cdy);
            double cv = d; int ci = a;
#pragma unroll
            for (int p = 0; p < MAXF; p++) {
                bool better = (cv < ld[p]) || (cv == ld[p] && ci < lid[p]);
                double tv = ld[p]; int ti = lid[p];
                if (better) { ld[p] = cv; lid[p] = ci; cv = tv; ci = ti; }
            }
        }
        for (int off = 32; off; off >>= 1) cnt += __shfl_xor(cnt, off);
        if (lane == 0) atomicAdd(&s_cnt, cnt);
        for (int j = 0; j < MAXF; j++) {
            double bv = ld[0]; int bi = lid[0];
            int hi = lid[0];
            for (int off = 32; off; off >>= 1) {
                double ov = __shfl_xor(bv, off); int oi = __shfl_xor(bi, off);
                if (ov < bv || (ov == bv && oi < bi)) { bv = ov; bi = oi; }
            }
            if (lane == 0) { LwV[wid][j] = bv; LwI[wid][j] = bi; }
            if (hi == bi) {
#pragma unroll
                for (int p = 0; p < MAXF - 1; p++) { ld[p] = ld[p + 1]; lid[p] = lid[p + 1]; }
                ld[MAXF - 1] = 1e301; lid[MAXF - 1] = 0x7fffffff;
            }
        }
        __syncthreads();
        if (tid == 0) {
            int p0 = 0, p1 = 0, p2 = 0, p3 = 0;
            for (int j = 0; j < MAXF; j++) {
                double h0 = (p0 < MAXF) ? LwV[0][p0] : 1e302; int i0 = (p0 < MAXF) ? LwI[0][p0] : 0x7fffffff;
                double h1 = (p1 < MAXF) ? LwV[1][p1] : 1e302; int i1 = (p1 < MAXF) ? LwI[1][p1] : 0x7fffffff;
                double h2 = (p2 < MAXF) ? LwV[2][p2] : 1e302; int i2 = (p2 < MAXF) ? LwI[2][p2] : 0x7fffffff;
                double h3 = (p3 < MAXF) ? LwV[3][p3] : 1e302; int i3 = (p3 < MAXF) ? LwI[3][p3] : 0x7fffffff;
                double bv = h0; int bi = i0; int bw = 0;
                if (h1 < bv || (h1 == bv && i1 < bi)) { bv = h1; bi = i1; bw = 1; }
                if (h2 < bv || (h2 == bv && i2 < bi)) { bv = h2; bi = i2; bw = 2; }
                if (h3 < bv || (h3 == bv && i3 < bi)) { bv = h3; bi = i3; bw = 3; }
                s_win[j] = bi;
                if (bw == 0) p0++; else if (bw == 1) p1++; else if (bw == 2) p2++; else p3++;
            }
            int total = s_cnt;
            int k = 0;
            if (total == 0) k = (area < 0.002) ? 5 : 3;
            s_k = k;
            for (int j = 0; j < MAXF; j++) fb_idx[bg * MAXF + j] = s_win[j];
        }
        __syncthreads();
    }
    if (tid == 0) fb_cnt[bg] = s_k;

    if (m <= 0) {
        if (tid == 0) am_max[bg] = 0.0;
        return;
    }
    __syncthreads();

    double scale = sqrt(w * h);
    float scalef = (float)scale;
    float sef = scalef + 1e-6f;
    float se2f = scalef * 1.5f + 1e-6f;
    float iq1f = 1.0f / (sef * sef);
    float iq2f = 1.0f / (se2f * se2f);
    int lbl = gt_labels[bg];
    int fcnt = s_k;
    int fidx[MAXF];
#pragma unroll
    for (int t = 0; t < MAXF; t++) fidx[t] = need_fb ? s_win[t] : 0x7fffffff;

    // ---- Phase A: algebraic f32 bounds (no transcendentals); ub -> LDS, lb -> top-10 ----
    unsigned long long inmask = 0ull;
    float lb10[KTOP];
#pragma unroll
    for (int t = 0; t < KTOP; t++) lb10[t] = -3.0e38f;

    {
        int i = 0;
        for (int a = tid; a < NA; a += 256, ++i) {
            float axf = anchor_points[2 * a], ayf = anchor_points[2 * a + 1];
            double cdx = (double)axf - cx, cdy = (double)ayf - cy;
            double ldx = cdx * ct - cdy * st;
            double ldy = cdx * st + cdy * ct;
            bool inb = (fabs(ldx) < w15) && (fabs(ldy) < h15);
            bool fbh = false;
#pragma unroll
            for (int t = 0; t < MAXF; t++) if (t < fcnt && fidx[t] == a) fbh = true;
            float ub = -3.0e38f;
            if (inb || fbh) {
                inmask |= (1ull << i);
                float pxf = pred_bboxes[((size_t)b * NA + a) * 5 + 0];
                float pyf = pred_bboxes[((size_t)b * NA + a) * 5 + 1];
                float lgsf = lg32[((size_t)b * NA + a) * NC + lbl];
                float dxf = pxf - cxf, dyf = pyf - cyf;
                float r2 = (dxf * dxf + dyf * dyf) * iq1f;
                float cdxf = axf - cxf, cdyf = ayf - cyf;
                float cr2 = (cdxf * cdxf + cdyf * cdyf) * iq2f;
                float lb;
                t_bounds(lgsf, r2, cr2, lb, ub);
#pragma unroll
                for (int p = 0; p < KTOP; p++) {
                    bool better = lb > lb10[p];
                    float tv = lb10[p];
                    if (better) { lb10[p] = lb; lb = tv; }
                }
            }
            s_ub[a] = ub;
        }
    }
    // wave-exact 10th of lb (indexless merge; ties pop together -> sound, weaker)
    {
        float bv = -3.0e38f;
        for (int j = 0; j < KTOP; j++) {
            bv = lb10[0];
            for (int off = 32; off; off >>= 1)
                bv = fmaxf(bv, __shfl_xor(bv, off));
            if (lb10[0] == bv) {
#pragma unroll
                for (int p = 0; p < KTOP - 1; p++) lb10[p] = lb10[p + 1];
                lb10[KTOP - 1] = -3.0e38f;
            }
        }
        if (lane == 0) atomicMax(&s_bar_u, fenc(bv));
    }
    __syncthreads();
    float bar_t = fdec(s_bar_u);
    bool skip_ok = (bar_t > -700.0f);   // false when bar unfilled (NaN/-3e38) or underflow regime

    // ---- Phase B: f64 eval of survivors only (ub from LDS) ----
    double lv[KTOP]; int li[KTOP];
#pragma unroll
    for (int t = 0; t < KTOP; t++) { lv[t] = -1.0; li[t] = 0x7fffffff; }

    {
        int i = 0;
        for (int a = tid; a < NA; a += 256, ++i) {
            bool act = (inmask >> i) & 1ull;
            double amm; bool have = false;
            if (act) {
                if (!skip_ok || s_ub[a] >= bar_t) {
                    float axf = anchor_points[2 * a], ayf = anchor_points[2 * a + 1];
                    float pxf = pred_bboxes[((size_t)b * NA + a) * 5 + 0];
                    float pyf = pred_bboxes[((size_t)b * NA + a) * 5 + 1];
                    double lgs = lgs64_of(pred_scores[((size_t)b * NA + a) * NC + lbl]);
                    double px = (double)pxf, py = (double)pyf;
                    double dx = px - cx, dy = py - cy;
                    double d  = sqrt(dx * dx + dy * dy);
                    double r  = d / (scale + 1e-6);
                    double e1 = exp(-(r * r));
                    double L  = log(e1 + 1e-9);
                    double cdx = (double)axf - cx, cdy = (double)ayf - cy;
                    double cd = sqrt(cdx * cdx + cdy * cdy);
                    double cr = cd / (scale * 1.5 + 1e-6);
                    amm = exp(0.5 * lgs + 6.0 * L - cr * cr);
                    have = true;
                }
            } else if (!skip_ok) {
                amm = 0.0; have = true;   // zeros compete only when <10 certified positives
            }
            if (have) {
                double cv = amm; int ci = a;
#pragma unroll
                for (int p = 0; p < KTOP; p++) {
                    bool better = (cv > lv[p]) || (cv == lv[p] && ci < li[p]);
                    double tv = lv[p]; int ti = li[p];
                    if (better) { lv[p] = cv; li[p] = ci; cv = tv; ci = ti; }
                }
            }
        }
    }

    // wave merge (desc, idx asc)
    for (int j = 0; j < KTOP; j++) {
        double bv = lv[0]; int bi = li[0];
        int hi = li[0];
        for (int off = 32; off; off >>= 1) {
            double ov = __shfl_xor(bv, off); int oi = __shfl_xor(bi, off);
            if (ov > bv || (ov == bv && oi < bi)) { bv = ov; bi = oi; }
        }
        if (lane == 0) { LwV[wid][j] = bv; LwI[wid][j] = bi; }
        if (hi == bi) {
#pragma unroll
            for (int p = 0; p < KTOP - 1; p++) { lv[p] = lv[p + 1]; li[p] = li[p + 1]; }
            lv[KTOP - 1] = -2.0; li[KTOP - 1] = 0x7fffffff;
        }
    }
    __syncthreads();

    if (tid == 0) {
        int p0 = 0, p1 = 0, p2 = 0, p3 = 0;
        for (int j = 0; j < KTOP; j++) {
            double h0 = (p0 < KTOP) ? LwV[0][p0] : -3.0; int i0 = (p0 < KTOP) ? LwI[0][p0] : 0x7fffffff;
            double h1 = (p1 < KTOP) ? LwV[1][p1] : -3.0; int i1 = (p1 < KTOP) ? LwI[1][p1] : 0x7fffffff;
            double h2 = (p2 < KTOP) ? LwV[2][p2] : -3.0; int i2 = (p2 < KTOP) ? LwI[2][p2] : 0x7fffffff;
            double h3 = (p3 < KTOP) ? LwV[3][p3] : -3.0; int i3 = (p3 < KTOP) ? LwI[3][p3] : 0x7fffffff;
            double bv = h0; int bi = i0; int bw = 0;
            if (h1 > bv || (h1 == bv && i1 < bi)) { bv = h1; bi = i1; bw = 1; }
            if (h2 > bv || (h2 == bv && i2 < bi)) { bv = h2; bi = i2; bw = 2; }
            if (h3 > bv || (h3 == bv && i3 < bi)) { bv = h3; bi = i3; bw = 3; }
            wv_s[j] = bv; wi_s[j] = bi;
            if (bw == 0) p0++; else if (bw == 1) p1++; else if (bw == 2) p2++; else p3++;
        }
        am_max[bg] = wv_s[0];
        double ssum = 0.0;
        for (int j = 0; j < KTOP; j++) {
            int aW = wi_s[j];
            double px = (double)pred_bboxes[((size_t)b * NA + aW) * 5 + 0];
            double py = (double)pred_bboxes[((size_t)b * NA + aW) * 5 + 1];
            double dx = px - cx, dy = py - cy;
            double d = sqrt(dx * dx + dy * dy);
            double r = d / (scale + 1e-6);
            ssum += exp(-(r * r));
        }
        double rk = rint(ssum);
        rk = fmin(fmax(rk, 1.0), 10.0);
        for (int j = 0; j < KTOP; j++) {
            if (wv_s[j] > 1e-9 && (double)j < rk)
                atomicOr(&pos_mask[b * NA + wi_s[j]], 1);
        }
    }
}

// ---------- K2: per-anchor argmax (g-sliced) two-phase + outputs ----------

__global__ __launch_bounds__(256) void k_final(
    const float* __restrict__ pred_scores,
    const float* __restrict__ pred_bboxes,
    const float* __restrict__ anchor_points,
    const int*   __restrict__ gt_labels,
    const float* __restrict__ gt_bboxes,
    const int*   __restrict__ mask_gt,
    const float* __restrict__ lg32,
    const int*   __restrict__ fb_cnt,
    const int*   __restrict__ fb_idx,
    const double* __restrict__ am_max,
    const int*   __restrict__ pos_mask,
    float* __restrict__ out)
{
    __shared__ double s_cx[NG], s_cy[NG], s_ct[NG], s_st[NG], s_scale[NG], s_w15[NG], s_h15[NG], s_am[NG];
    __shared__ float  f_cx[NG], f_cy[NG], f_iq1[NG], f_iq2[NG];
    __shared__ int s_lbl[NG], s_msk[NG], s_fcnt[NG];
    __shared__ int s_fidx[NG][MAXF];
    __shared__ double mv[4][64];
    __shared__ int    mg[4][64];
    __shared__ double mo[4][64];
    __shared__ float  barr[4][64];

    int b = blockIdx.y;
    int tid = threadIdx.x;
    if (tid < NG) {
        int g = tid, bgi = b * NG + g;
        const float* gbb = gt_bboxes + (size_t)bgi * 5;
        double th = gbb[4];
        double w = gbb[2], h = gbb[3];
        s_cx[g] = gbb[0]; s_cy[g] = gbb[1];
        s_w15[g] = w * 1.5; s_h15[g] = h * 1.5;
        s_ct[g] = cos(-th); s_st[g] = sin(-th);
        double sc = sqrt(w * h);
        s_scale[g] = sc;
        f_cx[g] = gbb[0]; f_cy[g] = gbb[1];
        float scf = (float)sc;
        float sef = scf + 1e-6f, se2f = scf * 1.5f + 1e-6f;
        f_iq1[g] = 1.0f / (sef * sef);
        f_iq2[g] = 1.0f / (se2f * se2f);
        s_am[g] = am_max[bgi];
        s_lbl[g] = gt_labels[bgi];
        s_msk[g] = mask_gt[bgi];
        s_fcnt[g] = fb_cnt[bgi];
        for (int t = 0; t < MAXF; t++) s_fidx[g][t] = fb_idx[bgi * MAXF + t];
    }
    __syncthreads();

    int al = tid & 63;
    int slice = tid >> 6;
    int g0 = slice * 32;
    int a = blockIdx.x * 64 + al;
    bool okA = (a < NA);

    float pxf = 0.f, pyf = 0.f, axf = 0.f, ayf = 0.f;
    float l0 = 0.f, l1 = 0.f, l2 = 0.f, l3 = 0.f, l4 = 0.f;
    unsigned actmask = 0u;
    float bestlb = -3.0e38f;

    if (okA) {
        pxf = pred_bboxes[((size_t)b * NA + a) * 5 + 0];
        pyf = pred_bboxes[((size_t)b * NA + a) * 5 + 1];
        axf = anchor_points[2 * a]; ayf = anchor_points[2 * a + 1];
        const float* lg = lg32 + ((size_t)b * NA + a) * NC;
        l0 = lg[0]; l1 = lg[1]; l2 = lg[2]; l3 = lg[3]; l4 = lg[4];

        // Phase A: algebraic bounds over this slice's 32 gts
        for (int k = 0; k < 32; k++) {
            int g = g0 + k;
            double cdx = (double)axf - s_cx[g], cdy = (double)ayf - s_cy[g];
            double ldx = cdx * s_ct[g] - cdy * s_st[g];
            double ldy = cdx * s_st[g] + cdy * s_ct[g];
            bool inb = (fabs(ldx) < s_w15[g]) && (fabs(ldy) < s_h15[g]);
            bool fbh = false;
            int fc = s_fcnt[g];
#pragma unroll
            for (int t = 0; t < MAXF; t++) if (t < fc && s_fidx[g][t] == a) fbh = true;
            if ((inb || fbh) && s_msk[g] > 0) {
                actmask |= (1u << k);
                int lbl = s_lbl[g];
                float lgsf = (lbl == 0) ? l0 : (lbl == 1) ? l1 : (lbl == 2) ? l2 : (lbl == 3) ? l3 : l4;
                float dxf = pxf - f_cx[g], dyf = pyf - f_cy[g];
                float r2 = (dxf * dxf + dyf * dyf) * f_iq1[g];
                float cdxf = axf - f_cx[g], cdyf = ayf - f_cy[g];
                float cr2 = (cdxf * cdxf + cdyf * cdyf) * f_iq2[g];
                float lb, ub;
                t_bounds(lgsf, r2, cr2, lb, ub);
                bestlb = fmaxf(bestlb, lb);
            }
        }
    }
    barr[slice][al] = bestlb;
    __syncthreads();
    float bar_a = fmaxf(fmaxf(barr[0][al], barr[1][al]), fmaxf(barr[2][al], barr[3][al]));
    bool skip_ok = (bar_a > -700.0f);

    double best = 0.0; int bestg = g0; double bov = 0.0;
    if (okA) {
        // Phase B: f64 eval of surviving gts, ascending g (first-max semantics)
        for (int k = 0; k < 32; k++) {
            if (!((actmask >> k) & 1u)) continue;
            int g = g0 + k;
            if (skip_ok) {
                int lbl = s_lbl[g];
                float lgsf = (lbl == 0) ? l0 : (lbl == 1) ? l1 : (lbl == 2) ? l2 : (lbl == 3) ? l3 : l4;
                float dxf = pxf - f_cx[g], dyf = pyf - f_cy[g];
                float r2 = (dxf * dxf + dyf * dyf) * f_iq1[g];
                float cdxf = axf - f_cx[g], cdyf = ayf - f_cy[g];
                float cr2 = (cdxf * cdxf + cdyf * cdyf) * f_iq2[g];
                float lb, ub;
                t_bounds(lgsf, r2, cr2, lb, ub);
                if (ub < bar_a) continue;   // provably below the anchor's max
            }
            int lbl = s_lbl[g];
            double lgs = lgs64_of(pred_scores[((size_t)b * NA + a) * NC + lbl]);
            double px = (double)pxf, py = (double)pyf;
            double dx = px - s_cx[g], dy = py - s_cy[g];
            double d = sqrt(dx * dx + dy * dy);
            double r = d / (s_scale[g] + 1e-6);
            double e1 = exp(-(r * r));
            double L = log(e1 + 1e-9);
            double cdx = (double)axf - s_cx[g], cdy = (double)ayf - s_cy[g];
            double cd = sqrt(cdx * cdx + cdy * cdy);
            double cr = cd / (s_scale[g] * 1.5 + 1e-6);
            double amm = exp(0.5 * lgs + 6.0 * L - cr * cr);
            if (amm > best) { best = amm; bestg = g; bov = e1; }
        }
    }

    mv[slice][al] = best; mg[slice][al] = bestg; mo[slice][al] = bov;
    __syncthreads();

    if (tid < 64) {
        int a2 = blockIdx.x * 64 + tid;
        if (a2 < NA) {
            double B = mv[0][tid]; int G = mg[0][tid]; double OV = mo[0][tid];
#pragma unroll
            for (int s = 1; s < 4; s++) {
                if (mv[s][tid] > B) { B = mv[s][tid]; G = mg[s][tid]; OV = mo[s][tid]; }
            }
            int lbl = s_lbl[G];
            bool pos = pos_mask[b * NA + a2] != 0;
            bool valid = (lbl >= 0 && lbl < NC) && pos;
            double raw = B / (s_am[G] + 1e-9) * OV;
            double soft = (raw > 0.0) ? sqrt(raw) : 0.0;

            size_t ba = (size_t)b * NA + a2;
            out[ba] = (float)lbl;
            const float* gb2 = gt_bboxes + ((size_t)b * NG + G) * 5;
            float* ob = out + (size_t)NB * NA + ba * 5;
            ob[0] = gb2[0]; ob[1] = gb2[1]; ob[2] = gb2[2]; ob[3] = gb2[3]; ob[4] = gb2[4];
            float* os = out + (size_t)NB * NA * 6 + ba * 5;
            float sval = valid ? (float)soft : 0.0f;
#pragma unroll
            for (int c = 0; c < NC; c++) os[c] = (c == lbl) ? sval : 0.0f;
            out[(size_t)NB * NA * 11 + ba] = pos ? 1.0f : 0.0f;
        }
    }
}

// ---------- launch ----------

extern "C" void kernel_launch(void* const* d_in, const int* in_sizes, int n_in,
                              void* d_out, int out_size, void* d_ws, size_t ws_size,
                              hipStream_t stream)
{
    const float* pred_scores   = (const float*)d_in[0];
    const float* pred_bboxes   = (const float*)d_in[1];
    const float* anchor_points = (const float*)d_in[2];
    const int*   gt_labels     = (const int*)d_in[3];
    const float* gt_bboxes     = (const float*)d_in[4];
    const int*   mask_gt       = (const int*)d_in[5];
    float* out = (float*)d_out;

    char* ws = (char*)d_ws;
    size_t off = 0;
    int* pos_mask = (int*)(ws + off);
    off += (size_t)NB * NA * sizeof(int);
    off = (off + 255) & ~(size_t)255;
    double* amax = (double*)(ws + off);
    off += (size_t)NB * NG * sizeof(double);
    off = (off + 255) & ~(size_t)255;
    int* fb_cnt = (int*)(ws + off);
    off += (size_t)NB * NG * sizeof(int);
    off = (off + 255) & ~(size_t)255;
    int* fb_idx = (int*)(ws + off);
    off += (size_t)NB * NG * MAXF * sizeof(int);
    off = (off + 255) & ~(size_t)255;
    float* lg32 = (float*)(ws + off);

    int nls = NB * NA * NC;
    k_prep<<<(nls + 255) / 256, 256, 0, stream>>>(pred_scores, lg32, pos_mask);
    k_assign<<<NB * NG, 256, 0, stream>>>(pred_scores, pred_bboxes, anchor_points, gt_labels,
                                          gt_bboxes, mask_gt, lg32,
                                          fb_cnt, fb_idx, amax, pos_mask);
    k_final<<<dim3((NA + 63) / 64, NB), 256, 0, stream>>>(
        pred_scores, pred_bboxes, anchor_points, gt_labels, gt_bboxes, mask_gt, lg32,
        fb_cnt, fb_idx, amax, pos_mask, out);
}